// Round 2
// 2446.826 us; speedup vs baseline: 2.1189x; 2.1189x over previous
//
#include <hip/hip_runtime.h>

#define TSTEPS 512
#define DK 512       // D == H == 512
#define NC 2048      // 4H

typedef unsigned int u32;
typedef unsigned short u16;
typedef __attribute__((ext_vector_type(8))) short bf16x8;
typedef __attribute__((ext_vector_type(4))) float f32x4;
typedef __attribute__((ext_vector_type(4))) unsigned int u32x4;

static __device__ __forceinline__ float bf2f(u16 u) {
    return __uint_as_float(((u32)u) << 16);
}
static __device__ __forceinline__ u16 f2bf(float f) {
    u32 u = __float_as_uint(f);
    u += 0x7fffu + ((u >> 16) & 1u);
    return (u16)(u >> 16);
}
static __device__ __forceinline__ float sigmoidf_(float x) { return 1.0f / (1.0f + __expf(-x)); }
static __device__ __forceinline__ float tanhf_(float x)    { return 1.0f - 2.0f / (__expf(2.0f * x) + 1.0f); }

// MFMA A/B fragment address (u16 units) for element (k, n) of a 16xK (or Kx16)
// operand: K0=k>>5 block of 1024 B; lane L = n | (((k>>3)&3)<<4); sub j = k&7.
static __device__ __forceinline__ int fragaddr(int k, int n) {
    return ((k >> 5) << 9) + ((n | (((k >> 3) & 3) << 4)) << 3) + (k & 7);
}

// ---- system-scope (MALL coherence point) bypass ops: no fence needed -------
static __device__ __forceinline__ void st_u16_sys(u16* p, u16 v) {
    asm volatile("global_store_short %0, %1, off sc0 sc1"
                 :: "v"(p), "v"((u32)v) : "memory");
}
static __device__ __forceinline__ void st_u32_sys(u32* p, u32 v) {
    asm volatile("global_store_dword %0, %1, off sc0 sc1"
                 :: "v"(p), "v"(v) : "memory");
}
static __device__ __forceinline__ u32 ld_u32_sys(const u32* p) {
    u32 v;
    asm volatile("global_load_dword %0, %1, off sc0 sc1\n\t"
                 "s_waitcnt vmcnt(0)"
                 : "=v"(v) : "v"(p) : "memory");
    return v;
}

// ---------------------------------------------------------------------------
// K1: transposed-output GEMM (unchanged, verified rounds 3-4).
// xwt[(t*NC + c)*64 + b] = bf16( sum_k x[b][t][k]*Wx[k][c] + bias[c] )
// ---------------------------------------------------------------------------
__global__ __launch_bounds__(256)
void gemm_xwt(const float* __restrict__ x, const float* __restrict__ Wx,
              const float* __restrict__ bias, u16* __restrict__ xwt) {
    __shared__ float As[16][64];
    __shared__ float Bs[16][68];
    const int tid = threadIdx.x;
    const int t   = blockIdx.x;
    const int c0  = blockIdx.y * 64;
    const int lk  = tid >> 4;
    const int lc  = (tid & 15) << 2;
    const int lb  = tid >> 2;
    const int lkx = (tid & 3) << 2;
    const int tc  = tid & 15;
    const int tb  = tid >> 4;
    float acc[4][4] = {};
    for (int k0 = 0; k0 < DK; k0 += 16) {
        const float4 av = *(const float4*)(Wx + (size_t)(k0 + lk) * NC + c0 + lc);
        const float4 bv = *(const float4*)(x + ((size_t)lb * TSTEPS + t) * DK + k0 + lkx);
        __syncthreads();
        *(float4*)&As[lk][lc] = av;
        Bs[lkx + 0][lb] = bv.x;
        Bs[lkx + 1][lb] = bv.y;
        Bs[lkx + 2][lb] = bv.z;
        Bs[lkx + 3][lb] = bv.w;
        __syncthreads();
        #pragma unroll
        for (int k = 0; k < 16; ++k) {
            float a4[4], b4[4];
            *(float4*)a4 = *(const float4*)&As[k][tc << 2];
            *(float4*)b4 = *(const float4*)&Bs[k][tb << 2];
            #pragma unroll
            for (int i = 0; i < 4; ++i)
                #pragma unroll
                for (int j = 0; j < 4; ++j)
                    acc[i][j] += a4[i] * b4[j];
        }
    }
    const float4 bias4 = *(const float4*)(bias + c0 + (tc << 2));
    const float bi[4] = {bias4.x, bias4.y, bias4.z, bias4.w};
    #pragma unroll
    for (int i = 0; i < 4; ++i) {
        const size_t row = (size_t)t * NC + c0 + (tc << 2) + i;
        ushort4 s;
        s.x = f2bf(acc[i][0] + bi[i]);
        s.y = f2bf(acc[i][1] + bi[i]);
        s.z = f2bf(acc[i][2] + bi[i]);
        s.w = f2bf(acc[i][3] + bi[i]);
        *(ushort4*)(xwt + row * 64 + (tb << 2)) = s;
    }
}

// ---------------------------------------------------------------------------
// Fallbacks (ws too small): round-1 kernels, [b][t][c] layout.
// ---------------------------------------------------------------------------
__global__ __launch_bounds__(256)
void gemm_xw(const float* __restrict__ x, const float* __restrict__ Wx,
             const float* __restrict__ bias, u16* __restrict__ xw_out) {
    __shared__ float As[16][68];
    __shared__ float Bs[16][64];
    const int tid  = threadIdx.x;
    const int tx   = tid & 15;
    const int ty   = tid >> 4;
    const int row0 = blockIdx.x * 64;
    const int col0 = blockIdx.y * 64;
    const int ar = tid >> 2;
    const int ak = (tid & 3) << 2;
    const int bk = tid >> 4;
    const int bc = (tid & 15) << 2;
    float acc[4][4] = {};
    for (int k0 = 0; k0 < DK; k0 += 16) {
        const float4 av = *(const float4*)(x  + (size_t)(row0 + ar) * DK + k0 + ak);
        const float4 bv = *(const float4*)(Wx + (size_t)(k0 + bk) * NC + col0 + bc);
        __syncthreads();
        As[ak + 0][ar] = av.x; As[ak + 1][ar] = av.y;
        As[ak + 2][ar] = av.z; As[ak + 3][ar] = av.w;
        *(float4*)&Bs[bk][bc] = bv;
        __syncthreads();
        #pragma unroll
        for (int k = 0; k < 16; ++k) {
            float a4[4], b4[4];
            *(float4*)a4 = *(const float4*)&As[k][ty << 2];
            *(float4*)b4 = *(const float4*)&Bs[k][tx << 2];
            #pragma unroll
            for (int i = 0; i < 4; ++i)
                #pragma unroll
                for (int j = 0; j < 4; ++j)
                    acc[i][j] += a4[i] * b4[j];
        }
    }
    #pragma unroll
    for (int i = 0; i < 4; ++i) {
        const size_t row = (size_t)row0 + (ty << 2) + i;
        const int    col = col0 + (tx << 2);
        ushort4 s;
        s.x = f2bf(acc[i][0] + bias[col + 0]);
        s.y = f2bf(acc[i][1] + bias[col + 1]);
        s.z = f2bf(acc[i][2] + bias[col + 2]);
        s.w = f2bf(acc[i][3] + bias[col + 3]);
        *(ushort4*)(xw_out + row * NC + col) = s;
    }
}

__global__ __launch_bounds__(512)
void lstm_rec_old(const u16* __restrict__ xw, const float* __restrict__ Wh,
                  const float* __restrict__ h0, float* __restrict__ out) {
    __shared__ float h_s[DK];
    __shared__ float c_s[DK];
    __shared__ float a_s[NC];
    const int b   = blockIdx.x;
    const int tid = threadIdx.x;
    const int q   = tid << 2;
    h_s[tid] = h0[(size_t)b * DK + tid];
    c_s[tid] = 0.0f;
    __syncthreads();
    for (int t = 0; t < TSTEPS; ++t) {
        const size_t rowoff = ((size_t)b * TSTEPS + t) * NC;
        const ushort4 xv = *(const ushort4*)(xw + rowoff + q);
        float4 acc;
        acc.x = bf2f(xv.x); acc.y = bf2f(xv.y); acc.z = bf2f(xv.z); acc.w = bf2f(xv.w);
        const float* wp = Wh + q;
        #pragma unroll 4
        for (int k = 0; k < DK; k += 4) {
            const float4 hk = *(const float4*)&h_s[k];
            const float4 w0 = *(const float4*)(wp + (size_t)(k + 0) * NC);
            const float4 w1 = *(const float4*)(wp + (size_t)(k + 1) * NC);
            const float4 w2 = *(const float4*)(wp + (size_t)(k + 2) * NC);
            const float4 w3 = *(const float4*)(wp + (size_t)(k + 3) * NC);
            acc.x += hk.x * w0.x + hk.y * w1.x + hk.z * w2.x + hk.w * w3.x;
            acc.y += hk.x * w0.y + hk.y * w1.y + hk.z * w2.y + hk.w * w3.y;
            acc.z += hk.x * w0.z + hk.y * w1.z + hk.z * w2.z + hk.w * w3.z;
            acc.w += hk.x * w0.w + hk.y * w1.w + hk.z * w2.w + hk.w * w3.w;
        }
        *(float4*)&a_s[q] = acc;
        __syncthreads();
        const float ig = sigmoidf_(a_s[tid]);
        const float fg = sigmoidf_(a_s[DK + tid]);
        const float og = sigmoidf_(a_s[2 * DK + tid]);
        const float gg = tanhf_(a_s[3 * DK + tid]);
        const float c  = fg * c_s[tid] + ig * gg;
        const float h  = og * tanhf_(c);
        c_s[tid] = c;
        h_s[tid] = h;
        out[((size_t)b * TSTEPS + t) * DK + tid] = h;
        __syncthreads();
    }
}

// ---------------------------------------------------------------------------
__global__ void init_flg(u32* flg) {
    const int i = threadIdx.x;
    if (i < 128) flg[i] = 0u;
}

// ---------------------------------------------------------------------------
// K2 (v7): v5's verified structure + fence-free system-scope bypass protocol.
// 128 WGs x 256 thr = 4 batch-groups (i, 16 b) x 32 unit-groups (j, 16 u).
// All cross-WG traffic (h publish, flags, h stage) uses sc0 sc1 flat ops:
// stores write through L1/L2 to MALL; loads bypass L1/L2 and read MALL.
// Correctness: __syncthreads drains vmcnt(0) in every wave (h stores complete
// at the coherence point) BEFORE tid0 issues the flag store; a consumer that
// observes flag >= t+1 via a bypass load then issues bypass staging loads,
// which cannot hit stale cached lines -> no buffer_inv, no buffer_wbl2, no
// agent fences anywhere in the per-step chain (v5's 8.2us/step cost).
// Datapath (fragaddr layout, Bf preload, dual hi/lo bf16 MFMA chains,
// Cx/gates/out) is identical to the verified v5 kernel.
// ---------------------------------------------------------------------------
__global__ __launch_bounds__(256, 1)
void lstm_rec7(const u16* __restrict__ xwt, const float* __restrict__ Wh,
               const float* __restrict__ h0, float* __restrict__ out,
               u16* __restrict__ hG, u32* flg) {
    __shared__ __align__(16) u16 hF[2][8192];   // [hi/lo][frag order]  32 KB
    __shared__ float Cx[4][16][17];             // [gate][unit][b'] pad  4.25 KB
    __shared__ float hT[256];                   // [unit][b']            1 KB
    __shared__ int deadS;

    const int tid  = threadIdx.x;
    const int lane = tid & 63;
    const int wv   = __builtin_amdgcn_readfirstlane(tid >> 6);  // wave = gate
    const int g    = blockIdx.x;
    const int j    = g & 31;       // unit-group
    const int i    = g >> 5;       // batch-group
    const int du   = tid >> 4;     // gate-phase: local unit 0..15
    const int bp   = tid & 15;     // gate-phase: local batch 0..15
    const int u    = 16 * j + du;  // global unit
    const int b    = 16 * i + bp;  // global batch

    if (tid == 0) deadS = 0;

    // ---- h0 publish into hG buf 0, plane i (frag order, hi+lo, bypass)
    {
        const float h0v = h0[(size_t)b * DK + u];
        const u16 hi = f2bf(h0v);
        const u16 lo = f2bf(h0v - bf2f(hi));
        u16* dst = hG + ((size_t)0 * 4 + i) * 2 * 8192;
        const int fa = fragaddr(u, bp);
        st_u16_sys(dst + fa, hi);
        st_u16_sys(dst + 8192 + fa, lo);
    }
    float creg = 0.0f;
    __syncthreads();   // drains all waves' vmcnt: h0 at coherence point
    if (tid == 0) st_u32_sys(&flg[(i << 5) + j], 1u);

    // ---- B-fragment preload to VGPRs: Bf[K0][jj] = Wh[k][wv*512+16j+(lane&15)]
    bf16x8 Bf[16];
    {
        const int coln = 16 * j + (lane & 15);
        #pragma unroll
        for (int K0 = 0; K0 < 16; ++K0) {
            bf16x8 bv;
            #pragma unroll
            for (int jj = 0; jj < 8; ++jj) {
                const int k = K0 * 32 + ((lane >> 4) << 3) + jj;
                bv[jj] = (short)f2bf(Wh[(size_t)k * NC + wv * 512 + coln]);
            }
            Bf[K0] = bv;
        }
    }

    const u32* fp = &flg[(i << 5) + (lane & 31)];  // group's 128B flag region

    for (int t = 0; t < TSTEPS; ++t) {
        // xw prefetch (coalesced 32B runs), in flight during the poll
        const u16* xp = xwt + (size_t)t * (NC * 64);
        const u16 x0 = xp[(0 * 512 + u) * 64 + b];
        const u16 x1 = xp[(1 * 512 + u) * 64 + b];
        const u16 x2 = xp[(2 * 512 + u) * 64 + b];
        const u16 x3 = xp[(3 * 512 + u) * 64 + b];

        // ---- wait for group-i h(t): bypass polls of the group's flag words
        {
            const u32 target = (u32)(t + 1);
            int spins = 0;
            while (true) {
                const u32 v = ld_u32_sys(fp);
                if (__all((int)(v >= target))) break;
                if (++spins > (1 << 18)) { if (lane == 0) deadS = 1; break; }
                __builtin_amdgcn_s_sleep(1);
            }
        }

        // ---- stage 32 KB (hi+lo planes) via bypass dwordx4 -> LDS
        {
            const char* srcb = (const char*)(hG + ((size_t)(t & 1) * 4 + i) * 2 * 8192);
            const char* p0 = srcb + (size_t)tid * 16;
            u32x4 q0, q1, q2, q3, q4, q5, q6, q7;
            asm volatile("global_load_dwordx4 %0, %1, off sc0 sc1" : "=v"(q0) : "v"(p0));
            asm volatile("global_load_dwordx4 %0, %1, off sc0 sc1" : "=v"(q1) : "v"(p0 + 4096));
            asm volatile("global_load_dwordx4 %0, %1, off sc0 sc1" : "=v"(q2) : "v"(p0 + 8192));
            asm volatile("global_load_dwordx4 %0, %1, off sc0 sc1" : "=v"(q3) : "v"(p0 + 12288));
            asm volatile("global_load_dwordx4 %0, %1, off sc0 sc1" : "=v"(q4) : "v"(p0 + 16384));
            asm volatile("global_load_dwordx4 %0, %1, off sc0 sc1" : "=v"(q5) : "v"(p0 + 20480));
            asm volatile("global_load_dwordx4 %0, %1, off sc0 sc1" : "=v"(q6) : "v"(p0 + 24576));
            asm volatile("global_load_dwordx4 %0, %1, off sc0 sc1" : "=v"(q7) : "v"(p0 + 28672));
            asm volatile("s_waitcnt vmcnt(0)" ::: "memory");
            __builtin_amdgcn_sched_barrier(0);
            u32* d32 = (u32*)&hF[0][0];
            *(u32x4*)(d32 + 0 * 1024 + tid * 4) = q0;
            *(u32x4*)(d32 + 1 * 1024 + tid * 4) = q1;
            *(u32x4*)(d32 + 2 * 1024 + tid * 4) = q2;
            *(u32x4*)(d32 + 3 * 1024 + tid * 4) = q3;
            *(u32x4*)(d32 + 4 * 1024 + tid * 4) = q4;
            *(u32x4*)(d32 + 5 * 1024 + tid * 4) = q5;
            *(u32x4*)(d32 + 6 * 1024 + tid * 4) = q6;
            *(u32x4*)(d32 + 7 * 1024 + tid * 4) = q7;
        }
        __syncthreads();
        if (deadS) break;          // uniform after barrier; loud-fail, no hang

        // ---- MFMA: acc[16b x 16cols] over K=512, hi+lo accumulated separately
        f32x4 acc_h = {0.f, 0.f, 0.f, 0.f};
        f32x4 acc_l = {0.f, 0.f, 0.f, 0.f};
        #pragma unroll
        for (int K0 = 0; K0 < 16; ++K0) {
            const bf16x8 ah = *(const bf16x8*)&hF[0][K0 * 512 + lane * 8];
            const bf16x8 al = *(const bf16x8*)&hF[1][K0 * 512 + lane * 8];
            acc_h = __builtin_amdgcn_mfma_f32_16x16x32_bf16(ah, Bf[K0], acc_h, 0, 0, 0);
            acc_l = __builtin_amdgcn_mfma_f32_16x16x32_bf16(al, Bf[K0], acc_l, 0, 0, 0);
        }
        const f32x4 accv = acc_h + acc_l;

        // C layout: col=lane&15 (unit), row=(lane>>4)*4+r (b'). -> Cx[gate][unit][b']
        #pragma unroll
        for (int r = 0; r < 4; ++r)
            Cx[wv][lane & 15][((lane >> 4) << 2) + r] = accv[r];
        __syncthreads();

        // ---- gate phase: thread (du, bp)
        const float ai = Cx[0][du][bp] + bf2f(x0);
        const float af = Cx[1][du][bp] + bf2f(x1);
        const float ao = Cx[2][du][bp] + bf2f(x2);
        const float ag = Cx[3][du][bp] + bf2f(x3);
        const float ig = sigmoidf_(ai);
        const float fg = sigmoidf_(af);
        const float og = sigmoidf_(ao);
        const float gg = tanhf_(ag);
        creg = fg * creg + ig * gg;
        const float hnew = og * tanhf_(creg);

        // publish h(t+1) (frag order, hi+lo, bypass write-through)
        {
            const u16 hi = f2bf(hnew);
            const u16 lo = f2bf(hnew - bf2f(hi));
            u16* dst = hG + ((size_t)((t + 1) & 1) * 4 + i) * 2 * 8192;
            const int fa = fragaddr(u, bp);
            st_u16_sys(dst + fa, hi);
            st_u16_sys(dst + 8192 + fa, lo);
        }
        hT[tid] = hnew;   // hT[du*16+bp]
        __syncthreads();  // publish stores drained in every wave + hT visible

        if (tid == 0) st_u32_sys(&flg[(i << 5) + j], (u32)(t + 2));

        if (wv == 0) {    // out[b][t][16j+qd*4 .. +4]
            const int bq = lane >> 2;
            const int qd = lane & 3;
            float4 o4;
            o4.x = hT[(qd * 4 + 0) * 16 + bq];
            o4.y = hT[(qd * 4 + 1) * 16 + bq];
            o4.z = hT[(qd * 4 + 2) * 16 + bq];
            o4.w = hT[(qd * 4 + 3) * 16 + bq];
            *(float4*)(out + ((size_t)(16 * i + bq) * TSTEPS + t) * DK + 16 * j + qd * 4) = o4;
        }
    }
}

// ---------------------------------------------------------------------------
extern "C" void kernel_launch(void* const* d_in, const int* in_sizes, int n_in,
                              void* d_out, int out_size, void* d_ws, size_t ws_size,
                              hipStream_t stream) {
    const float* x    = (const float*)d_in[0];
    const float* h0   = (const float*)d_in[1];
    const float* Wx   = (const float*)d_in[2];
    const float* Wh   = (const float*)d_in[3];
    const float* bias = (const float*)d_in[4];
    float* out = (float*)d_out;

    u16* xw = (u16*)d_ws;
    const size_t XW_BYTES = (size_t)TSTEPS * NC * 64 * sizeof(u16);   // 134217728
    u16* hG  = (u16*)((char*)d_ws + XW_BYTES);                        // 256 KB
    u32* flg = (u32*)((char*)d_ws + XW_BYTES + 262144);               // 4x32 u32, line-aligned
    const size_t need = XW_BYTES + 262144 + 512;

    if (ws_size >= need) {
        dim3 g1(TSTEPS, 32);
        gemm_xwt<<<g1, 256, 0, stream>>>(x, Wx, bias, xw);
        init_flg<<<1, 128, 0, stream>>>(flg);
        lstm_rec7<<<128, 256, 0, stream>>>(xw, Wh, h0, out, hG, flg);
    } else {
        dim3 g1(512, 32);
        gemm_xw<<<g1, 256, 0, stream>>>(x, Wx, bias, xw);
        lstm_rec_old<<<64, 512, 0, stream>>>(xw, Wh, h0, out);
    }
}

// Round 4
// 1916.328 us; speedup vs baseline: 2.7054x; 1.2768x over previous
//
#include <hip/hip_runtime.h>

#define TSTEPS 512
#define DK 512       // D == H == 512
#define NC 2048      // 4H

typedef unsigned int u32;
typedef unsigned short u16;
typedef __attribute__((ext_vector_type(8))) short bf16x8;
typedef __attribute__((ext_vector_type(4))) float f32x4;
typedef __attribute__((ext_vector_type(4))) unsigned int u32x4;
typedef __attribute__((ext_vector_type(2))) unsigned int u32x2;

static __device__ __forceinline__ float bf2f(u16 u) {
    return __uint_as_float(((u32)u) << 16);
}
static __device__ __forceinline__ u16 f2bf(float f) {
    u32 u = __float_as_uint(f);
    u += 0x7fffu + ((u >> 16) & 1u);
    return (u16)(u >> 16);
}
static __device__ __forceinline__ float sigmoidf_(float x) { return 1.0f / (1.0f + __expf(-x)); }
static __device__ __forceinline__ float tanhf_(float x)    { return 1.0f - 2.0f / (__expf(2.0f * x) + 1.0f); }

// MFMA A/B fragment address (u16 units) for element (k, n) of a 16xK (or Kx16)
// operand: K0=k>>5 block of 1024 B; lane L = n | (((k>>3)&3)<<4); sub j = k&7.
static __device__ __forceinline__ int fragaddr(int k, int n) {
    return ((k >> 5) << 9) + ((n | (((k >> 3) & 3) << 4)) << 3) + (k & 7);
}

// ---- system-scope (MALL coherence point) bypass ops: no fence needed -------
static __device__ __forceinline__ void st_u16_sys(u16* p, u16 v) {
    asm volatile("global_store_short %0, %1, off sc0 sc1"
                 :: "v"(p), "v"((u32)v) : "memory");
}
static __device__ __forceinline__ void st_u32_sys(u32* p, u32 v) {
    asm volatile("global_store_dword %0, %1, off sc0 sc1"
                 :: "v"(p), "v"(v) : "memory");
}
static __device__ __forceinline__ u32 ld_u32_sys(const u32* p) {
    u32 v;
    asm volatile("global_load_dword %0, %1, off sc0 sc1\n\t"
                 "s_waitcnt vmcnt(0)"
                 : "=v"(v) : "v"(p) : "memory");
    return v;
}

// ---------------------------------------------------------------------------
// K1 (v9): MFMA GEMM for xwt. Same bf16 hi/lo scheme the recurrence verified:
// x split hi+lo bf16 (A-fragments, fragaddr layout), Wx rounded once to bf16
// (B-fragments in VGPRs, like Wh), dual-plane 16x16x32 MFMA accumulate, bias
// added in fp32, one f2bf round at the end.
// Block = (t, 64 cols); 4 b-tiles of 16 looped inside. Grid t-major so the
// 32 c-blocks of slice t share the 131KB x-slice in L2.
// xwt[(t*NC + c)*64 + b] = bf16( sum_k x[b][t][k]*Wx[k][c] + bias[c] )
// ---------------------------------------------------------------------------
__global__ __launch_bounds__(256)
void gemm_xwt_mfma(const float* __restrict__ x, const float* __restrict__ Wx,
                   const float* __restrict__ bias, u16* __restrict__ xwt) {
    __shared__ __align__(16) u16 xF[2][8192];   // [hi/lo][frag order] 32 KB
    const int tid  = threadIdx.x;
    const int lane = tid & 63;
    const int wv   = __builtin_amdgcn_readfirstlane(tid >> 6);  // wave = 16-col group
    const int bid  = (int)blockIdx.x;
    const int t    = bid >> 5;          // t-major dispatch
    const int cb   = bid & 31;
    const int c0   = cb << 6;           // block cols [c0, c0+64)

    // ---- B-fragment preload: Bf[K0][jj] = bf16(Wx[k][c0 + wv*16 + (lane&15)])
    bf16x8 Bf[16];
    const int coln = c0 + wv * 16 + (lane & 15);
    {
        #pragma unroll
        for (int K0 = 0; K0 < 16; ++K0) {
            bf16x8 bv;
            #pragma unroll
            for (int jj = 0; jj < 8; ++jj) {
                const int k = K0 * 32 + ((lane >> 4) << 3) + jj;
                bv[jj] = (short)f2bf(Wx[(size_t)k * NC + coln]);
            }
            Bf[K0] = bv;
        }
    }
    const float bi = bias[coln];

    const int n  = tid >> 4;            // b-row within tile (0..15)
    const int q0 = (tid & 15) << 2;     // k-quad base (0,4,..,60)

    for (int bt = 0; bt < 4; ++bt) {
        const float* xp = x + ((size_t)(bt * 16 + n) * TSTEPS + t) * DK;
        __syncthreads();                // protect previous iteration's reads
        #pragma unroll
        for (int kq = 0; kq < 8; ++kq) {
            const int k = q0 + kq * 64;
            const float4 xv = *(const float4*)(xp + k);
            u16 h0_ = f2bf(xv.x), h1_ = f2bf(xv.y), h2_ = f2bf(xv.z), h3_ = f2bf(xv.w);
            u16 l0_ = f2bf(xv.x - bf2f(h0_));
            u16 l1_ = f2bf(xv.y - bf2f(h1_));
            u16 l2_ = f2bf(xv.z - bf2f(h2_));
            u16 l3_ = f2bf(xv.w - bf2f(h3_));
            const int fa = ((k >> 5) << 9) + ((n | (((k >> 3) & 3) << 4)) << 3) + (k & 7);
            u32x2 ph, pl;
            ph[0] = (u32)h0_ | ((u32)h1_ << 16);
            ph[1] = (u32)h2_ | ((u32)h3_ << 16);
            pl[0] = (u32)l0_ | ((u32)l1_ << 16);
            pl[1] = (u32)l2_ | ((u32)l3_ << 16);
            *(u32x2*)&xF[0][fa] = ph;
            *(u32x2*)&xF[1][fa] = pl;
        }
        __syncthreads();

        f32x4 acc_h = {0.f, 0.f, 0.f, 0.f};
        f32x4 acc_l = {0.f, 0.f, 0.f, 0.f};
        #pragma unroll
        for (int K0 = 0; K0 < 16; ++K0) {
            const bf16x8 ah = *(const bf16x8*)&xF[0][K0 * 512 + lane * 8];
            const bf16x8 al = *(const bf16x8*)&xF[1][K0 * 512 + lane * 8];
            acc_h = __builtin_amdgcn_mfma_f32_16x16x32_bf16(ah, Bf[K0], acc_h, 0, 0, 0);
            acc_l = __builtin_amdgcn_mfma_f32_16x16x32_bf16(al, Bf[K0], acc_l, 0, 0, 0);
        }
        const f32x4 accv = acc_h + acc_l;

        // D: col = lane&15 (c-local), row = (lane>>4)*4 + r (b-local).
        // xwt row (t*NC + c) has 64 consecutive b -> 4 consecutive u16 = 8B store.
        const u16 s0 = f2bf(accv[0] + bi);
        const u16 s1 = f2bf(accv[1] + bi);
        const u16 s2 = f2bf(accv[2] + bi);
        const u16 s3 = f2bf(accv[3] + bi);
        u32x2 sv;
        sv[0] = (u32)s0 | ((u32)s1 << 16);
        sv[1] = (u32)s2 | ((u32)s3 << 16);
        const size_t row = (size_t)t * NC + coln;
        *(u32x2*)(xwt + row * 64 + bt * 16 + ((lane >> 4) << 2)) = sv;
    }
}

// ---------------------------------------------------------------------------
// Fallbacks (ws too small): round-1 kernels, [b][t][c] layout.
// ---------------------------------------------------------------------------
__global__ __launch_bounds__(256)
void gemm_xw(const float* __restrict__ x, const float* __restrict__ Wx,
             const float* __restrict__ bias, u16* __restrict__ xw_out) {
    __shared__ float As[16][68];
    __shared__ float Bs[16][64];
    const int tid  = threadIdx.x;
    const int tx   = tid & 15;
    const int ty   = tid >> 4;
    const int row0 = blockIdx.x * 64;
    const int col0 = blockIdx.y * 64;
    const int ar = tid >> 2;
    const int ak = (tid & 3) << 2;
    const int bk = tid >> 4;
    const int bc = (tid & 15) << 2;
    float acc[4][4] = {};
    for (int k0 = 0; k0 < DK; k0 += 16) {
        const float4 av = *(const float4*)(x  + (size_t)(row0 + ar) * DK + k0 + ak);
        const float4 bv = *(const float4*)(Wx + (size_t)(k0 + bk) * NC + col0 + bc);
        __syncthreads();
        As[ak + 0][ar] = av.x; As[ak + 1][ar] = av.y;
        As[ak + 2][ar] = av.z; As[ak + 3][ar] = av.w;
        *(float4*)&Bs[bk][bc] = bv;
        __syncthreads();
        #pragma unroll
        for (int k = 0; k < 16; ++k) {
            float a4[4], b4[4];
            *(float4*)a4 = *(const float4*)&As[k][ty << 2];
            *(float4*)b4 = *(const float4*)&Bs[k][tx << 2];
            #pragma unroll
            for (int i = 0; i < 4; ++i)
                #pragma unroll
                for (int j = 0; j < 4; ++j)
                    acc[i][j] += a4[i] * b4[j];
        }
    }
    #pragma unroll
    for (int i = 0; i < 4; ++i) {
        const size_t row = (size_t)row0 + (ty << 2) + i;
        const int    col = col0 + (tx << 2);
        ushort4 s;
        s.x = f2bf(acc[i][0] + bias[col + 0]);
        s.y = f2bf(acc[i][1] + bias[col + 1]);
        s.z = f2bf(acc[i][2] + bias[col + 2]);
        s.w = f2bf(acc[i][3] + bias[col + 3]);
        *(ushort4*)(xw_out + row * NC + col) = s;
    }
}

__global__ __launch_bounds__(512)
void lstm_rec_old(const u16* __restrict__ xw, const float* __restrict__ Wh,
                  const float* __restrict__ h0, float* __restrict__ out) {
    __shared__ float h_s[DK];
    __shared__ float c_s[DK];
    __shared__ float a_s[NC];
    const int b   = blockIdx.x;
    const int tid = threadIdx.x;
    const int q   = tid << 2;
    h_s[tid] = h0[(size_t)b * DK + tid];
    c_s[tid] = 0.0f;
    __syncthreads();
    for (int t = 0; t < TSTEPS; ++t) {
        const size_t rowoff = ((size_t)b * TSTEPS + t) * NC;
        const ushort4 xv = *(const ushort4*)(xw + rowoff + q);
        float4 acc;
        acc.x = bf2f(xv.x); acc.y = bf2f(xv.y); acc.z = bf2f(xv.z); acc.w = bf2f(xv.w);
        const float* wp = Wh + q;
        #pragma unroll 4
        for (int k = 0; k < DK; k += 4) {
            const float4 hk = *(const float4*)&h_s[k];
            const float4 w0 = *(const float4*)(wp + (size_t)(k + 0) * NC);
            const float4 w1 = *(const float4*)(wp + (size_t)(k + 1) * NC);
            const float4 w2 = *(const float4*)(wp + (size_t)(k + 2) * NC);
            const float4 w3 = *(const float4*)(wp + (size_t)(k + 3) * NC);
            acc.x += hk.x * w0.x + hk.y * w1.x + hk.z * w2.x + hk.w * w3.x;
            acc.y += hk.x * w0.y + hk.y * w1.y + hk.z * w2.y + hk.w * w3.y;
            acc.z += hk.x * w0.z + hk.y * w1.z + hk.z * w2.z + hk.w * w3.z;
            acc.w += hk.x * w0.w + hk.y * w1.w + hk.z * w2.w + hk.w * w3.w;
        }
        *(float4*)&a_s[q] = acc;
        __syncthreads();
        const float ig = sigmoidf_(a_s[tid]);
        const float fg = sigmoidf_(a_s[DK + tid]);
        const float og = sigmoidf_(a_s[2 * DK + tid]);
        const float gg = tanhf_(a_s[3 * DK + tid]);
        const float c  = fg * c_s[tid] + ig * gg;
        const float h  = og * tanhf_(c);
        c_s[tid] = c;
        h_s[tid] = h;
        out[((size_t)b * TSTEPS + t) * DK + tid] = h;
        __syncthreads();
    }
}

// ---------------------------------------------------------------------------
__global__ void init_flg(u32* flg) {
    const int i = threadIdx.x;
    if (i < 128) flg[i] = 0u;
}

// ---------------------------------------------------------------------------
// K2 (v7, verified round 2): fence-free system-scope bypass protocol.
// 128 WGs x 256 thr = 4 batch-groups (i, 16 b) x 32 unit-groups (j, 16 u).
// All cross-WG traffic (h publish, flags, h stage) uses sc0 sc1 flat ops:
// stores write through L1/L2 to MALL; loads bypass L1/L2 and read MALL.
// __syncthreads drains vmcnt(0) in every wave before tid0's flag store.
// BYTE-IDENTICAL to the round-2 passing kernel.
// ---------------------------------------------------------------------------
__global__ __launch_bounds__(256, 1)
void lstm_rec7(const u16* __restrict__ xwt, const float* __restrict__ Wh,
               const float* __restrict__ h0, float* __restrict__ out,
               u16* __restrict__ hG, u32* flg) {
    __shared__ __align__(16) u16 hF[2][8192];   // [hi/lo][frag order]  32 KB
    __shared__ float Cx[4][16][17];             // [gate][unit][b'] pad  4.25 KB
    __shared__ float hT[256];                   // [unit][b']            1 KB
    __shared__ int deadS;

    const int tid  = threadIdx.x;
    const int lane = tid & 63;
    const int wv   = __builtin_amdgcn_readfirstlane(tid >> 6);  // wave = gate
    const int g    = blockIdx.x;
    const int j    = g & 31;       // unit-group
    const int i    = g >> 5;       // batch-group
    const int du   = tid >> 4;     // gate-phase: local unit 0..15
    const int bp   = tid & 15;     // gate-phase: local batch 0..15
    const int u    = 16 * j + du;  // global unit
    const int b    = 16 * i + bp;  // global batch

    if (tid == 0) deadS = 0;

    // ---- h0 publish into hG buf 0, plane i (frag order, hi+lo, bypass)
    {
        const float h0v = h0[(size_t)b * DK + u];
        const u16 hi = f2bf(h0v);
        const u16 lo = f2bf(h0v - bf2f(hi));
        u16* dst = hG + ((size_t)0 * 4 + i) * 2 * 8192;
        const int fa = fragaddr(u, bp);
        st_u16_sys(dst + fa, hi);
        st_u16_sys(dst + 8192 + fa, lo);
    }
    float creg = 0.0f;
    __syncthreads();   // drains all waves' vmcnt: h0 at coherence point
    if (tid == 0) st_u32_sys(&flg[(i << 5) + j], 1u);

    // ---- B-fragment preload to VGPRs: Bf[K0][jj] = Wh[k][wv*512+16j+(lane&15)]
    bf16x8 Bf[16];
    {
        const int coln = 16 * j + (lane & 15);
        #pragma unroll
        for (int K0 = 0; K0 < 16; ++K0) {
            bf16x8 bv;
            #pragma unroll
            for (int jj = 0; jj < 8; ++jj) {
                const int k = K0 * 32 + ((lane >> 4) << 3) + jj;
                bv[jj] = (short)f2bf(Wh[(size_t)k * NC + wv * 512 + coln]);
            }
            Bf[K0] = bv;
        }
    }

    const u32* fp = &flg[(i << 5) + (lane & 31)];  // group's 128B flag region

    for (int t = 0; t < TSTEPS; ++t) {
        // xw prefetch (coalesced 32B runs), in flight during the poll
        const u16* xp = xwt + (size_t)t * (NC * 64);
        const u16 x0 = xp[(0 * 512 + u) * 64 + b];
        const u16 x1 = xp[(1 * 512 + u) * 64 + b];
        const u16 x2 = xp[(2 * 512 + u) * 64 + b];
        const u16 x3 = xp[(3 * 512 + u) * 64 + b];

        // ---- wait for group-i h(t): bypass polls of the group's flag words
        {
            const u32 target = (u32)(t + 1);
            int spins = 0;
            while (true) {
                const u32 v = ld_u32_sys(fp);
                if (__all((int)(v >= target))) break;
                if (++spins > (1 << 18)) { if (lane == 0) deadS = 1; break; }
                __builtin_amdgcn_s_sleep(1);
            }
        }

        // ---- stage 32 KB (hi+lo planes) via bypass dwordx4 -> LDS
        {
            const char* srcb = (const char*)(hG + ((size_t)(t & 1) * 4 + i) * 2 * 8192);
            const char* p0 = srcb + (size_t)tid * 16;
            u32x4 q0, q1, q2, q3, q4, q5, q6, q7;
            asm volatile("global_load_dwordx4 %0, %1, off sc0 sc1" : "=v"(q0) : "v"(p0));
            asm volatile("global_load_dwordx4 %0, %1, off sc0 sc1" : "=v"(q1) : "v"(p0 + 4096));
            asm volatile("global_load_dwordx4 %0, %1, off sc0 sc1" : "=v"(q2) : "v"(p0 + 8192));
            asm volatile("global_load_dwordx4 %0, %1, off sc0 sc1" : "=v"(q3) : "v"(p0 + 12288));
            asm volatile("global_load_dwordx4 %0, %1, off sc0 sc1" : "=v"(q4) : "v"(p0 + 16384));
            asm volatile("global_load_dwordx4 %0, %1, off sc0 sc1" : "=v"(q5) : "v"(p0 + 20480));
            asm volatile("global_load_dwordx4 %0, %1, off sc0 sc1" : "=v"(q6) : "v"(p0 + 24576));
            asm volatile("global_load_dwordx4 %0, %1, off sc0 sc1" : "=v"(q7) : "v"(p0 + 28672));
            asm volatile("s_waitcnt vmcnt(0)" ::: "memory");
            __builtin_amdgcn_sched_barrier(0);
            u32* d32 = (u32*)&hF[0][0];
            *(u32x4*)(d32 + 0 * 1024 + tid * 4) = q0;
            *(u32x4*)(d32 + 1 * 1024 + tid * 4) = q1;
            *(u32x4*)(d32 + 2 * 1024 + tid * 4) = q2;
            *(u32x4*)(d32 + 3 * 1024 + tid * 4) = q3;
            *(u32x4*)(d32 + 4 * 1024 + tid * 4) = q4;
            *(u32x4*)(d32 + 5 * 1024 + tid * 4) = q5;
            *(u32x4*)(d32 + 6 * 1024 + tid * 4) = q6;
            *(u32x4*)(d32 + 7 * 1024 + tid * 4) = q7;
        }
        __syncthreads();
        if (deadS) break;          // uniform after barrier; loud-fail, no hang

        // ---- MFMA: acc[16b x 16cols] over K=512, hi+lo accumulated separately
        f32x4 acc_h = {0.f, 0.f, 0.f, 0.f};
        f32x4 acc_l = {0.f, 0.f, 0.f, 0.f};
        #pragma unroll
        for (int K0 = 0; K0 < 16; ++K0) {
            const bf16x8 ah = *(const bf16x8*)&hF[0][K0 * 512 + lane * 8];
            const bf16x8 al = *(const bf16x8*)&hF[1][K0 * 512 + lane * 8];
            acc_h = __builtin_amdgcn_mfma_f32_16x16x32_bf16(ah, Bf[K0], acc_h, 0, 0, 0);
            acc_l = __builtin_amdgcn_mfma_f32_16x16x32_bf16(al, Bf[K0], acc_l, 0, 0, 0);
        }
        const f32x4 accv = acc_h + acc_l;

        // C layout: col=lane&15 (unit), row=(lane>>4)*4+r (b'). -> Cx[gate][unit][b']
        #pragma unroll
        for (int r = 0; r < 4; ++r)
            Cx[wv][lane & 15][((lane >> 4) << 2) + r] = accv[r];
        __syncthreads();

        // ---- gate phase: thread (du, bp)
        const float ai = Cx[0][du][bp] + bf2f(x0);
        const float af = Cx[1][du][bp] + bf2f(x1);
        const float ao = Cx[2][du][bp] + bf2f(x2);
        const float ag = Cx[3][du][bp] + bf2f(x3);
        const float ig = sigmoidf_(ai);
        const float fg = sigmoidf_(af);
        const float og = sigmoidf_(ao);
        const float gg = tanhf_(ag);
        creg = fg * creg + ig * gg;
        const float hnew = og * tanhf_(creg);

        // publish h(t+1) (frag order, hi+lo, bypass write-through)
        {
            const u16 hi = f2bf(hnew);
            const u16 lo = f2bf(hnew - bf2f(hi));
            u16* dst = hG + ((size_t)((t + 1) & 1) * 4 + i) * 2 * 8192;
            const int fa = fragaddr(u, bp);
            st_u16_sys(dst + fa, hi);
            st_u16_sys(dst + 8192 + fa, lo);
        }
        hT[tid] = hnew;   // hT[du*16+bp]
        __syncthreads();  // publish stores drained in every wave + hT visible

        if (tid == 0) st_u32_sys(&flg[(i << 5) + j], (u32)(t + 2));

        if (wv == 0) {    // out[b][t][16j+qd*4 .. +4]
            const int bq = lane >> 2;
            const int qd = lane & 3;
            float4 o4;
            o4.x = hT[(qd * 4 + 0) * 16 + bq];
            o4.y = hT[(qd * 4 + 1) * 16 + bq];
            o4.z = hT[(qd * 4 + 2) * 16 + bq];
            o4.w = hT[(qd * 4 + 3) * 16 + bq];
            *(float4*)(out + ((size_t)(16 * i + bq) * TSTEPS + t) * DK + 16 * j + qd * 4) = o4;
        }
    }
}

// ---------------------------------------------------------------------------
extern "C" void kernel_launch(void* const* d_in, const int* in_sizes, int n_in,
                              void* d_out, int out_size, void* d_ws, size_t ws_size,
                              hipStream_t stream) {
    const float* x    = (const float*)d_in[0];
    const float* h0   = (const float*)d_in[1];
    const float* Wx   = (const float*)d_in[2];
    const float* Wh   = (const float*)d_in[3];
    const float* bias = (const float*)d_in[4];
    float* out = (float*)d_out;

    u16* xw = (u16*)d_ws;
    const size_t XW_BYTES = (size_t)TSTEPS * NC * 64 * sizeof(u16);   // 134217728
    u16* hG  = (u16*)((char*)d_ws + XW_BYTES);                        // 256 KB
    u32* flg = (u32*)((char*)d_ws + XW_BYTES + 262144);               // 4x32 u32, line-aligned
    const size_t need = XW_BYTES + 262144 + 512;

    if (ws_size >= need) {
        gemm_xwt_mfma<<<TSTEPS * 32, 256, 0, stream>>>(x, Wx, bias, xw);
        init_flg<<<1, 128, 0, stream>>>(flg);
        lstm_rec7<<<128, 256, 0, stream>>>(xw, Wh, h0, out, hG, flg);
    } else {
        dim3 g1(512, 32);
        gemm_xw<<<g1, 256, 0, stream>>>(x, Wx, bias, xw);
        lstm_rec_old<<<64, 512, 0, stream>>>(xw, Wh, h0, out);
    }
}

// Round 5
// 1466.824 us; speedup vs baseline: 3.5345x; 1.3064x over previous
//
#include <hip/hip_runtime.h>

#define TSTEPS 512
#define DK 512       // D == H == 512
#define NC 2048      // 4H
#define TB 4         // t-slices per GEMM block

typedef unsigned int u32;
typedef unsigned short u16;
typedef _Float16 f16x8 __attribute__((ext_vector_type(8)));
typedef __attribute__((ext_vector_type(4))) float f32x4;
typedef __attribute__((ext_vector_type(4))) unsigned int u32x4;
typedef __attribute__((ext_vector_type(2))) unsigned int u32x2;

static __device__ __forceinline__ u16 f2h(float f) {
    _Float16 h = (_Float16)f;
    u16 u; __builtin_memcpy(&u, &h, 2); return u;
}
static __device__ __forceinline__ float h2f(u16 u) {
    _Float16 h; __builtin_memcpy(&h, &u, 2); return (float)h;
}
static __device__ __forceinline__ u16 f2bf(float f) {
    u32 u = __float_as_uint(f);
    u += 0x7fffu + ((u >> 16) & 1u);
    return (u16)(u >> 16);
}
static __device__ __forceinline__ float sigmoidf_(float x) { return 1.0f / (1.0f + __expf(-x)); }
static __device__ __forceinline__ float tanhf_(float x)    { return 1.0f - 2.0f / (__expf(2.0f * x) + 1.0f); }

// MFMA A/B fragment address (u16 units) for element (k, n) of a 16xK (or Kx16)
// operand: K0=k>>5 block of 1024 B; lane L = n | (((k>>3)&3)<<4); sub j = k&7.
static __device__ __forceinline__ int fragaddr(int k, int n) {
    return ((k >> 5) << 9) + ((n | (((k >> 3) & 3) << 4)) << 3) + (k & 7);
}

// ---- system-scope (MALL coherence point) bypass ops: no fence needed -------
static __device__ __forceinline__ void st_u16_sys(u16* p, u16 v) {
    asm volatile("global_store_short %0, %1, off sc0 sc1"
                 :: "v"(p), "v"((u32)v) : "memory");
}
static __device__ __forceinline__ void st_u32_sys(u32* p, u32 v) {
    asm volatile("global_store_dword %0, %1, off sc0 sc1"
                 :: "v"(p), "v"(v) : "memory");
}
static __device__ __forceinline__ u32 ld_u32_sys(const u32* p) {
    u32 v;
    asm volatile("global_load_dword %0, %1, off sc0 sc1\n\t"
                 "s_waitcnt vmcnt(0)"
                 : "=v"(v) : "v"(p) : "memory");
    return v;
}

// ---------------------------------------------------------------------------
// K1 (v10): f16 MFMA GEMM for xwt, TB=4 t-slices per block (Wx B-fragments
// preloaded once, reused 4x). Single-plane f16 (11-bit mantissa beats the
// verified bf16 hi-plane-only W rounding). Layouts identical to v9.
// xwt[(t*NC + c)*64 + b] = f16( sum_k x[b][t][k]*Wx[k][c] + bias[c] )
// ---------------------------------------------------------------------------
__global__ __launch_bounds__(256)
void gemm_xwt_f16(const float* __restrict__ x, const float* __restrict__ Wx,
                  const float* __restrict__ bias, u16* __restrict__ xwt) {
    __shared__ __align__(16) u16 xF[8192];      // f16 frag order, 16 KB
    const int tid  = threadIdx.x;
    const int lane = tid & 63;
    const int wv   = __builtin_amdgcn_readfirstlane(tid >> 6);  // wave = 16-col group
    const int bid  = (int)blockIdx.x;
    const int tt   = bid >> 5;          // t-group (4 slices)
    const int cb   = bid & 31;
    const int c0   = cb << 6;           // block cols [c0, c0+64)

    // ---- B-fragment preload: Bf[K0][jj] = f16(Wx[k][c0 + wv*16 + (lane&15)])
    f16x8 Bf[16];
    const int coln = c0 + wv * 16 + (lane & 15);
    {
        #pragma unroll
        for (int K0 = 0; K0 < 16; ++K0) {
            f16x8 bv;
            #pragma unroll
            for (int jj = 0; jj < 8; ++jj) {
                const int k = K0 * 32 + ((lane >> 4) << 3) + jj;
                bv[jj] = (_Float16)Wx[(size_t)k * NC + coln];
            }
            Bf[K0] = bv;
        }
    }
    const float bi = bias[coln];

    const int n  = tid >> 4;            // b-row within tile (0..15)
    const int q0 = (tid & 15) << 2;     // k-quad base (0,4,..,60)

    for (int ts = 0; ts < TB; ++ts) {
        const int t = tt * TB + ts;
        for (int bt = 0; bt < 4; ++bt) {
            const float* xp = x + ((size_t)(bt * 16 + n) * TSTEPS + t) * DK;
            __syncthreads();            // protect previous iteration's reads
            #pragma unroll
            for (int kq = 0; kq < 8; ++kq) {
                const int k = q0 + kq * 64;
                const float4 xv = *(const float4*)(xp + k);
                const u16 h0_ = f2h(xv.x), h1_ = f2h(xv.y);
                const u16 h2_ = f2h(xv.z), h3_ = f2h(xv.w);
                const int fa = fragaddr(k, n);
                u32x2 ph;
                ph[0] = (u32)h0_ | ((u32)h1_ << 16);
                ph[1] = (u32)h2_ | ((u32)h3_ << 16);
                *(u32x2*)&xF[fa] = ph;
            }
            __syncthreads();

            f32x4 acc = {0.f, 0.f, 0.f, 0.f};
            #pragma unroll
            for (int K0 = 0; K0 < 16; ++K0) {
                const f16x8 av = *(const f16x8*)&xF[K0 * 512 + lane * 8];
                acc = __builtin_amdgcn_mfma_f32_16x16x32_f16(av, Bf[K0], acc, 0, 0, 0);
            }

            // D: col = lane&15 (c-local), row = (lane>>4)*4 + r (b-local).
            const u16 s0 = f2h(acc[0] + bi);
            const u16 s1 = f2h(acc[1] + bi);
            const u16 s2 = f2h(acc[2] + bi);
            const u16 s3 = f2h(acc[3] + bi);
            u32x2 sv;
            sv[0] = (u32)s0 | ((u32)s1 << 16);
            sv[1] = (u32)s2 | ((u32)s3 << 16);
            const size_t row = (size_t)t * NC + coln;
            *(u32x2*)(xwt + row * 64 + bt * 16 + ((lane >> 4) << 2)) = sv;
        }
    }
}

// ---------------------------------------------------------------------------
// Fallbacks (ws too small): round-1 kernels, [b][t][c] layout, fp32 exact-ish.
// ---------------------------------------------------------------------------
__global__ __launch_bounds__(256)
void gemm_xw(const float* __restrict__ x, const float* __restrict__ Wx,
             const float* __restrict__ bias, u16* __restrict__ xw_out) {
    __shared__ float As[16][68];
    __shared__ float Bs[16][64];
    const int tid  = threadIdx.x;
    const int tx   = tid & 15;
    const int ty   = tid >> 4;
    const int row0 = blockIdx.x * 64;
    const int col0 = blockIdx.y * 64;
    const int ar = tid >> 2;
    const int ak = (tid & 3) << 2;
    const int bk = tid >> 4;
    const int bc = (tid & 15) << 2;
    float acc[4][4] = {};
    for (int k0 = 0; k0 < DK; k0 += 16) {
        const float4 av = *(const float4*)(x  + (size_t)(row0 + ar) * DK + k0 + ak);
        const float4 bv = *(const float4*)(Wx + (size_t)(k0 + bk) * NC + col0 + bc);
        __syncthreads();
        As[ak + 0][ar] = av.x; As[ak + 1][ar] = av.y;
        As[ak + 2][ar] = av.z; As[ak + 3][ar] = av.w;
        *(float4*)&Bs[bk][bc] = bv;
        __syncthreads();
        #pragma unroll
        for (int k = 0; k < 16; ++k) {
            float a4[4], b4[4];
            *(float4*)a4 = *(const float4*)&As[k][ty << 2];
            *(float4*)b4 = *(const float4*)&Bs[k][tx << 2];
            #pragma unroll
            for (int i = 0; i < 4; ++i)
                #pragma unroll
                for (int j = 0; j < 4; ++j)
                    acc[i][j] += a4[i] * b4[j];
        }
    }
    #pragma unroll
    for (int i = 0; i < 4; ++i) {
        const size_t row = (size_t)row0 + (ty << 2) + i;
        const int    col = col0 + (tx << 2);
        ushort4 s;
        s.x = f2bf(acc[i][0] + bias[col + 0]);
        s.y = f2bf(acc[i][1] + bias[col + 1]);
        s.z = f2bf(acc[i][2] + bias[col + 2]);
        s.w = f2bf(acc[i][3] + bias[col + 3]);
        *(ushort4*)(xw_out + row * NC + col) = s;
    }
}

static __device__ __forceinline__ float bf2f(u16 u) {
    return __uint_as_float(((u32)u) << 16);
}

__global__ __launch_bounds__(512)
void lstm_rec_old(const u16* __restrict__ xw, const float* __restrict__ Wh,
                  const float* __restrict__ h0, float* __restrict__ out) {
    __shared__ float h_s[DK];
    __shared__ float c_s[DK];
    __shared__ float a_s[NC];
    const int b   = blockIdx.x;
    const int tid = threadIdx.x;
    const int q   = tid << 2;
    h_s[tid] = h0[(size_t)b * DK + tid];
    c_s[tid] = 0.0f;
    __syncthreads();
    for (int t = 0; t < TSTEPS; ++t) {
        const size_t rowoff = ((size_t)b * TSTEPS + t) * NC;
        const ushort4 xv = *(const ushort4*)(xw + rowoff + q);
        float4 acc;
        acc.x = bf2f(xv.x); acc.y = bf2f(xv.y); acc.z = bf2f(xv.z); acc.w = bf2f(xv.w);
        const float* wp = Wh + q;
        #pragma unroll 4
        for (int k = 0; k < DK; k += 4) {
            const float4 hk = *(const float4*)&h_s[k];
            const float4 w0 = *(const float4*)(wp + (size_t)(k + 0) * NC);
            const float4 w1 = *(const float4*)(wp + (size_t)(k + 1) * NC);
            const float4 w2 = *(const float4*)(wp + (size_t)(k + 2) * NC);
            const float4 w3 = *(const float4*)(wp + (size_t)(k + 3) * NC);
            acc.x += hk.x * w0.x + hk.y * w1.x + hk.z * w2.x + hk.w * w3.x;
            acc.y += hk.x * w0.y + hk.y * w1.y + hk.z * w2.y + hk.w * w3.y;
            acc.z += hk.x * w0.z + hk.y * w1.z + hk.z * w2.z + hk.w * w3.z;
            acc.w += hk.x * w0.w + hk.y * w1.w + hk.z * w2.w + hk.w * w3.w;
        }
        *(float4*)&a_s[q] = acc;
        __syncthreads();
        const float ig = sigmoidf_(a_s[tid]);
        const float fg = sigmoidf_(a_s[DK + tid]);
        const float og = sigmoidf_(a_s[2 * DK + tid]);
        const float gg = tanhf_(a_s[3 * DK + tid]);
        const float c  = fg * c_s[tid] + ig * gg;
        const float h  = og * tanhf_(c);
        c_s[tid] = c;
        h_s[tid] = h;
        out[((size_t)b * TSTEPS + t) * DK + tid] = h;
        __syncthreads();
    }
}

// ---------------------------------------------------------------------------
__global__ void init_flg(u32* flg) {
    const int i = threadIdx.x;
    if (i < 128) flg[i] = 0u;
}

// ---------------------------------------------------------------------------
// K2 (v10): v7's verified fence-free bypass protocol, f16 single-plane h.
// 128 WGs x 256 thr = 4 batch-groups (i, 16 b) x 32 unit-groups (j, 16 u).
// Per step: poll 32 flags -> stage 16 KB h (bypass dwordx4) -> 16 f16 MFMA
// -> Cx transpose -> gates -> publish h(t+1) f16 (1 store/thread) -> drain
// via __syncthreads -> flag. Protocol/barrier structure byte-identical to
// the round-2/round-4 passing kernel; only the payload dtype changed.
// ---------------------------------------------------------------------------
__global__ __launch_bounds__(256, 1)
void lstm_rec10(const u16* __restrict__ xwt, const float* __restrict__ Wh,
                const float* __restrict__ h0, float* __restrict__ out,
                u16* __restrict__ hG, u32* flg) {
    __shared__ __align__(16) u16 hF[8192];      // staged h, frag order, 16 KB
    __shared__ float Cx[4][16][17];             // [gate][unit][b'] pad  4.25 KB
    __shared__ float hT[256];                   // [unit][b']            1 KB
    __shared__ int deadS;

    const int tid  = threadIdx.x;
    const int lane = tid & 63;
    const int wv   = __builtin_amdgcn_readfirstlane(tid >> 6);  // wave = gate
    const int g    = blockIdx.x;
    const int j    = g & 31;       // unit-group
    const int i    = g >> 5;       // batch-group
    const int du   = tid >> 4;     // gate-phase: local unit 0..15
    const int bp   = tid & 15;     // gate-phase: local batch 0..15
    const int u    = 16 * j + du;  // global unit
    const int b    = 16 * i + bp;  // global batch

    if (tid == 0) deadS = 0;

    // ---- h0 publish into hG buf 0, plane i (frag order, f16, bypass)
    {
        const float h0v = h0[(size_t)b * DK + u];
        u16* dst = hG + ((size_t)0 * 4 + i) * 8192;
        st_u16_sys(dst + fragaddr(u, bp), f2h(h0v));
    }
    float creg = 0.0f;
    __syncthreads();   // drains all waves' vmcnt: h0 at coherence point
    if (tid == 0) st_u32_sys(&flg[(i << 5) + j], 1u);

    // ---- B-fragment preload to VGPRs: Bf[K0][jj] = f16(Wh[k][wv*512+16j+(lane&15)])
    f16x8 Bf[16];
    {
        const int coln = 16 * j + (lane & 15);
        #pragma unroll
        for (int K0 = 0; K0 < 16; ++K0) {
            f16x8 bv;
            #pragma unroll
            for (int jj = 0; jj < 8; ++jj) {
                const int k = K0 * 32 + ((lane >> 4) << 3) + jj;
                bv[jj] = (_Float16)Wh[(size_t)k * NC + wv * 512 + coln];
            }
            Bf[K0] = bv;
        }
    }

    const u32* fp = &flg[(i << 5) + (lane & 31)];  // group's 128B flag region

    for (int t = 0; t < TSTEPS; ++t) {
        // xw prefetch (coalesced 32B runs), in flight during the poll
        const u16* xp = xwt + (size_t)t * (NC * 64);
        const u16 x0 = xp[(0 * 512 + u) * 64 + b];
        const u16 x1 = xp[(1 * 512 + u) * 64 + b];
        const u16 x2 = xp[(2 * 512 + u) * 64 + b];
        const u16 x3 = xp[(3 * 512 + u) * 64 + b];

        // ---- wait for group-i h(t): bypass polls of the group's flag words
        {
            const u32 target = (u32)(t + 1);
            int spins = 0;
            while (true) {
                const u32 v = ld_u32_sys(fp);
                if (__all((int)(v >= target))) break;
                if (++spins > (1 << 18)) { if (lane == 0) deadS = 1; break; }
                __builtin_amdgcn_s_sleep(1);
            }
        }

        // ---- stage 16 KB (f16 plane) via bypass dwordx4 -> LDS
        {
            const char* srcb = (const char*)(hG + ((size_t)(t & 1) * 4 + i) * 8192);
            const char* p0 = srcb + (size_t)tid * 16;
            u32x4 q0, q1, q2, q3;
            asm volatile("global_load_dwordx4 %0, %1, off sc0 sc1" : "=v"(q0) : "v"(p0));
            asm volatile("global_load_dwordx4 %0, %1, off sc0 sc1" : "=v"(q1) : "v"(p0 + 4096));
            asm volatile("global_load_dwordx4 %0, %1, off sc0 sc1" : "=v"(q2) : "v"(p0 + 8192));
            asm volatile("global_load_dwordx4 %0, %1, off sc0 sc1" : "=v"(q3) : "v"(p0 + 12288));
            asm volatile("s_waitcnt vmcnt(0)" ::: "memory");
            __builtin_amdgcn_sched_barrier(0);
            u32* d32 = (u32*)&hF[0];
            *(u32x4*)(d32 + 0 * 1024 + tid * 4) = q0;
            *(u32x4*)(d32 + 1 * 1024 + tid * 4) = q1;
            *(u32x4*)(d32 + 2 * 1024 + tid * 4) = q2;
            *(u32x4*)(d32 + 3 * 1024 + tid * 4) = q3;
        }
        __syncthreads();
        if (deadS) break;          // uniform after barrier; loud-fail, no hang

        // ---- MFMA: acc[16b x 16cols] over K=512, f16 single chain
        f32x4 acc = {0.f, 0.f, 0.f, 0.f};
        #pragma unroll
        for (int K0 = 0; K0 < 16; ++K0) {
            const f16x8 ah = *(const f16x8*)&hF[K0 * 512 + lane * 8];
            acc = __builtin_amdgcn_mfma_f32_16x16x32_f16(ah, Bf[K0], acc, 0, 0, 0);
        }

        // C layout: col=lane&15 (unit), row=(lane>>4)*4+r (b'). -> Cx[gate][unit][b']
        #pragma unroll
        for (int r = 0; r < 4; ++r)
            Cx[wv][lane & 15][((lane >> 4) << 2) + r] = acc[r];
        __syncthreads();

        // ---- gate phase: thread (du, bp)
        const float ai = Cx[0][du][bp] + h2f(x0);
        const float af = Cx[1][du][bp] + h2f(x1);
        const float ao = Cx[2][du][bp] + h2f(x2);
        const float ag = Cx[3][du][bp] + h2f(x3);
        const float ig = sigmoidf_(ai);
        const float fg = sigmoidf_(af);
        const float og = sigmoidf_(ao);
        const float gg = tanhf_(ag);
        creg = fg * creg + ig * gg;
        const float hnew = og * tanhf_(creg);

        // publish h(t+1) (frag order, f16, bypass write-through)
        {
            u16* dst = hG + ((size_t)((t + 1) & 1) * 4 + i) * 8192;
            st_u16_sys(dst + fragaddr(u, bp), f2h(hnew));
        }
        hT[tid] = hnew;   // hT[du*16+bp]
        __syncthreads();  // publish stores drained in every wave + hT visible

        if (tid == 0) st_u32_sys(&flg[(i << 5) + j], (u32)(t + 2));

        if (wv == 0) {    // out[b][t][16j+qd*4 .. +4]
            const int bq = lane >> 2;
            const int qd = lane & 3;
            float4 o4;
            o4.x = hT[(qd * 4 + 0) * 16 + bq];
            o4.y = hT[(qd * 4 + 1) * 16 + bq];
            o4.z = hT[(qd * 4 + 2) * 16 + bq];
            o4.w = hT[(qd * 4 + 3) * 16 + bq];
            *(float4*)(out + ((size_t)(16 * i + bq) * TSTEPS + t) * DK + 16 * j + qd * 4) = o4;
        }
    }
}

// ---------------------------------------------------------------------------
extern "C" void kernel_launch(void* const* d_in, const int* in_sizes, int n_in,
                              void* d_out, int out_size, void* d_ws, size_t ws_size,
                              hipStream_t stream) {
    const float* x    = (const float*)d_in[0];
    const float* h0   = (const float*)d_in[1];
    const float* Wx   = (const float*)d_in[2];
    const float* Wh   = (const float*)d_in[3];
    const float* bias = (const float*)d_in[4];
    float* out = (float*)d_out;

    u16* xw = (u16*)d_ws;
    const size_t XW_BYTES = (size_t)TSTEPS * NC * 64 * sizeof(u16);   // 134217728
    u16* hG  = (u16*)((char*)d_ws + XW_BYTES);                        // 256 KB
    u32* flg = (u32*)((char*)d_ws + XW_BYTES + 262144);               // 4x32 u32, line-aligned
    const size_t need = XW_BYTES + 262144 + 512;

    if (ws_size >= need) {
        gemm_xwt_f16<<<(TSTEPS / TB) * 32, 256, 0, stream>>>(x, Wx, bias, xw);
        init_flg<<<1, 128, 0, stream>>>(flg);
        lstm_rec10<<<128, 256, 0, stream>>>(xw, Wh, h0, out, hG, flg);
    } else {
        dim3 g1(512, 32);
        gemm_xw<<<g1, 256, 0, stream>>>(x, Wx, bias, xw);
        lstm_rec_old<<<64, 512, 0, stream>>>(xw, Wh, h0, out);
    }
}